// Round 12
// baseline (669.949 us; speedup 1.0000x reference)
//
#include <hip/hip_runtime.h>
#include <math.h>

#define NN 100000
#define NE 1600000
#define DD 128
#define NL 3
#define LN_EPS 1e-5f
#define NRANGE 8
#define RSZ (NN / NRANGE)  // 12500

typedef __attribute__((ext_vector_type(8))) _Float16 f16x8;
typedef __attribute__((ext_vector_type(4))) float f32x4;
typedef unsigned short ushort_t;

__device__ __forceinline__ unsigned short f2h(float f) {
  _Float16 h = (_Float16)f;
  unsigned short u;
  __builtin_memcpy(&u, &h, 2);
  return u;
}
__device__ __forceinline__ float h2f(unsigned short u) {
  _Float16 h;
  __builtin_memcpy(&h, &u, 2);
  return (float)h;
}
// gelu with fast erf (A&S 7.1.26, |err|<1.5e-7 -- far below tolerance)
__device__ __forceinline__ float gelu_fast(float x) {
  float xs = x * 0.7071067811865476f;
  float ax = fabsf(xs);
  float t = __builtin_amdgcn_rcpf(fmaf(0.3275911f, ax, 1.0f));
  float p = fmaf(t, 1.061405429f, -1.453152027f);
  p = fmaf(t, p, 1.421413741f);
  p = fmaf(t, p, -0.284496736f);
  p = fmaf(t, p, 0.254829592f);
  p = p * t;
  float e = __expf(-ax * ax);
  float er = fmaf(-p, e, 1.0f);
  er = copysignf(er, xs);
  return 0.5f * x * (1.0f + er);
}

// ---------------- CSR build ----------------
// ONE atomic pass: k_count records each edge's slot (epos). k_fill then has
// ZERO atomics and stays XCD-ranged so scatter stores merge in the local L2.
__global__ __launch_bounds__(256) void k_count(const int* __restrict__ dst,
                                               int* __restrict__ deg,
                                               int* __restrict__ epos) {
  int e = blockIdx.x * blockDim.x + threadIdx.x;
  if (e < NE) epos[e] = atomicAdd(&deg[dst[e]], 1);
}

__global__ void k_block_sums(const int* __restrict__ deg, int* __restrict__ bsum) {
  __shared__ int sh[256];
  int t = threadIdx.x;
  int base = blockIdx.x * 1024;
  int s = 0;
#pragma unroll
  for (int j = 0; j < 4; j++) {
    int idx = base + t * 4 + j;
    if (idx < NN) s += deg[idx];
  }
  sh[t] = s;
  __syncthreads();
  for (int off = 128; off > 0; off >>= 1) {
    if (t < off) sh[t] += sh[t + off];
    __syncthreads();
  }
  if (t == 0) bsum[blockIdx.x] = sh[0];
}

__global__ void k_scan_sums(int* __restrict__ bsum, int nb) {
  __shared__ int sh[128];
  int t = threadIdx.x;
  int v = (t < nb) ? bsum[t] : 0;
  int acc = v;
  sh[t] = v;
  __syncthreads();
  for (int off = 1; off < 128; off <<= 1) {
    int o = (t >= off) ? sh[t - off] : 0;
    __syncthreads();
    acc += o;
    sh[t] = acc;
    __syncthreads();
  }
  if (t < nb) bsum[t] = acc - v;  // exclusive
}

__global__ void k_scan_write(const int* __restrict__ deg, const int* __restrict__ bsum,
                             int* __restrict__ rowstart) {
  __shared__ int sh[256];
  int t = threadIdx.x;
  int base = blockIdx.x * 1024;
  int idx0 = base + t * 4;
  int v[4];
  int s = 0;
#pragma unroll
  for (int j = 0; j < 4; j++) {
    int idx = idx0 + j;
    v[j] = (idx < NN) ? deg[idx] : 0;
    s += v[j];
  }
  int acc = s;
  sh[t] = s;
  __syncthreads();
  for (int off = 1; off < 256; off <<= 1) {
    int o = (t >= off) ? sh[t - off] : 0;
    __syncthreads();
    acc += o;
    sh[t] = acc;
    __syncthreads();
  }
  int excl = acc - s + bsum[blockIdx.x];
#pragma unroll
  for (int j = 0; j < 4; j++) {
    int idx = idx0 + j;
    if (idx < NN) rowstart[idx] = excl;
    excl += v[j];
  }
  if (blockIdx.x == 0 && t == 0) rowstart[NN] = NE;
}

__global__ __launch_bounds__(256) void k_fill(const int* __restrict__ src,
                                              const int* __restrict__ dst,
                                              const int* __restrict__ rowstart,
                                              const int* __restrict__ epos,
                                              int* __restrict__ csr) {
  int range = blockIdx.x & (NRANGE - 1);
  int lo = range * RSZ;
  int hi = lo + RSZ;
  int nblk = gridDim.x >> 3;
  int bid = blockIdx.x >> 3;
  for (int e = bid * 256 + threadIdx.x; e < NE; e += nblk * 256) {
    int d = dst[e];
    if (d >= lo && d < hi) {
      csr[rowstart[d] + epos[e]] = src[e];
    }
  }
}

// ---------------- W pre-pack into MFMA A-of-W^T fragment order (fp16) --------
// W1, pW: k = 32kk + 8q + j (natural order).
// W2:     k = 32kk + 16(j>>2) + 4q + (j&3) -- permutation that makes the
//         GEMM2 B-fragment equal the GEMM1' accumulator layout (no LDS xpose).
__global__ void k_pack(const float* __restrict__ W1, const float* __restrict__ W2,
                       const float* __restrict__ pW, ushort_t* __restrict__ wp) {
  int id = blockIdx.x * 256 + threadIdx.x;  // 7*16384
  int mtx = id >> 14;                       // 0..6
  int r = id & 16383;
  const float* src;
  int perm = 0;
  if (mtx == 6) {
    src = pW;  // natural pack: k_mm consumes memory-layout B-frags
  } else {
    int layer = mtx >> 1;
    if (mtx & 1) {
      src = W2 + layer * 16384;
      perm = 1;
    } else {
      src = W1 + layer * 16384;
    }
  }
  int j = r & 7;
  int l = (r >> 3) & 63;
  int kk = (r >> 9) & 3;
  int t = r >> 11;
  int qq = (l >> 4) & 3;
  int k = perm ? (kk * 32 + ((j >> 2) << 4) + (qq << 2) + (j & 3))
               : (kk * 32 + (qq << 3) + j);
  int n = t * 16 + (l & 15);
  wp[id] = f2h(src[k * DD + n]);
}

// ---------------- x -> fp16 h0 ----------------
__global__ void k_cast(const float* __restrict__ x, ushort_t* __restrict__ hb) {
  int i = blockIdx.x * 256 + threadIdx.x;  // over NN*DD/4
  if (i < NN * DD / 4) {
    float4 v = ((const float4*)x)[i];
    ushort4 o;
    o.x = f2h(v.x);
    o.y = f2h(v.y);
    o.z = f2h(v.z);
    o.w = f2h(v.w);
    ((ushort4*)hb)[i] = o;
  }
}

// ------- FUSED gather + MLP: z never leaves the CU ---------------------------
// Phase 1 (per wave): gather the wave's 16 node-rows (half-wave edge streams,
// 8 rows in flight) into a wave-private LDS tile [16][136] fp16 (272B rows,
// 16B-aligned; pad breaks the m-stride bank conflict on fragment reads).
// Phase 2: unchanged swapped-operand fp16 MFMA pipeline, z-frags from LDS.
// No __syncthreads anywhere -- the tile is wave-private.
template <int LAST>
__global__ __launch_bounds__(256, 4) void k_gmlp(
    const ushort_t* __restrict__ hb, const int* __restrict__ rowstart,
    const int* __restrict__ csr, const float* __restrict__ eps, int layer,
    const ushort_t* __restrict__ W1p, const ushort_t* __restrict__ W2p,
    const float* __restrict__ b1, const float* __restrict__ b2,
    const float* __restrict__ lng, const float* __restrict__ lnb,
    const ushort_t* __restrict__ hbprev1, ushort_t* __restrict__ hbout,
    const float* __restrict__ pg, const float* __restrict__ pbv,
    ushort_t* __restrict__ zo) {
  __shared__ ushort_t zt[4][16][136];
  int lane = threadIdx.x & 63;
  int wid = threadIdx.x >> 6;

  // ---- phase 1: gather 16 rows into LDS
  {
    int g = lane >> 5;   // half-wave edge-stream parity
    int ii = lane & 31;  // uint2 index within the 256B row
    const uint2* hb2 = (const uint2*)hb;
    float e1 = 1.0f + eps[layer];
    for (int j = 0; j < 16; j++) {
      int n = blockIdx.x * 64 + wid * 16 + j;
      if (n >= NN) n = NN - 1;
      float ga0 = 0.f, ga1 = 0.f, ga2 = 0.f, ga3 = 0.f;
      if (g == 0) {
        uint2 v = hb2[(size_t)n * 32 + ii];
        ga0 = e1 * h2f((ushort_t)(v.x & 0xffffu));
        ga1 = e1 * h2f((ushort_t)(v.x >> 16));
        ga2 = e1 * h2f((ushort_t)(v.y & 0xffffu));
        ga3 = e1 * h2f((ushort_t)(v.y >> 16));
      }
      float gb0 = 0.f, gb1 = 0.f, gb2 = 0.f, gb3 = 0.f;
      float gc0 = 0.f, gc1 = 0.f, gc2 = 0.f, gc3 = 0.f;
      float gd0 = 0.f, gd1 = 0.f, gd2 = 0.f, gd3 = 0.f;
      int s = rowstart[n], e = rowstart[n + 1];
      int k = s + g;
      for (; k + 6 < e; k += 8) {  // this half: edges k, k+2, k+4, k+6
        int i0 = csr[k], i1 = csr[k + 2], i2 = csr[k + 4], i3 = csr[k + 6];
        uint2 v0 = hb2[(size_t)i0 * 32 + ii];
        uint2 v1 = hb2[(size_t)i1 * 32 + ii];
        uint2 v2 = hb2[(size_t)i2 * 32 + ii];
        uint2 v3 = hb2[(size_t)i3 * 32 + ii];
        ga0 += h2f((ushort_t)(v0.x & 0xffffu));
        ga1 += h2f((ushort_t)(v0.x >> 16));
        ga2 += h2f((ushort_t)(v0.y & 0xffffu));
        ga3 += h2f((ushort_t)(v0.y >> 16));
        gb0 += h2f((ushort_t)(v1.x & 0xffffu));
        gb1 += h2f((ushort_t)(v1.x >> 16));
        gb2 += h2f((ushort_t)(v1.y & 0xffffu));
        gb3 += h2f((ushort_t)(v1.y >> 16));
        gc0 += h2f((ushort_t)(v2.x & 0xffffu));
        gc1 += h2f((ushort_t)(v2.x >> 16));
        gc2 += h2f((ushort_t)(v2.y & 0xffffu));
        gc3 += h2f((ushort_t)(v2.y >> 16));
        gd0 += h2f((ushort_t)(v3.x & 0xffffu));
        gd1 += h2f((ushort_t)(v3.x >> 16));
        gd2 += h2f((ushort_t)(v3.y & 0xffffu));
        gd3 += h2f((ushort_t)(v3.y >> 16));
      }
      for (; k < e; k += 2) {
        uint2 v = hb2[(size_t)csr[k] * 32 + ii];
        ga0 += h2f((ushort_t)(v.x & 0xffffu));
        ga1 += h2f((ushort_t)(v.x >> 16));
        ga2 += h2f((ushort_t)(v.y & 0xffffu));
        ga3 += h2f((ushort_t)(v.y >> 16));
      }
      ga0 += (gb0 + gc0) + gd0;
      ga1 += (gb1 + gc1) + gd1;
      ga2 += (gb2 + gc2) + gd2;
      ga3 += (gb3 + gc3) + gd3;
      ga0 += __shfl_xor(ga0, 32, 64);
      ga1 += __shfl_xor(ga1, 32, 64);
      ga2 += __shfl_xor(ga2, 32, 64);
      ga3 += __shfl_xor(ga3, 32, 64);
      if (g == 0) {
        uint2 o;
        o.x = (unsigned)f2h(ga0) | ((unsigned)f2h(ga1) << 16);
        o.y = (unsigned)f2h(ga2) | ((unsigned)f2h(ga3) << 16);
        *(uint2*)&zt[wid][j][ii * 4] = o;
      }
    }
  }

  // ---- phase 2: MFMA pipeline (z-frags from the wave's LDS tile)
  int m = lane & 15;
  int q = lane >> 4;
  int node = blockIdx.x * 64 + wid * 16 + m;
  int valid = node < NN;
  int node_c = valid ? node : (NN - 1);
  size_t base = (size_t)node_c * DD;

  f16x8 zf[4];
#pragma unroll
  for (int kk = 0; kk < 4; kk++)
    zf[kk] = *(const f16x8*)&zt[wid][m][kk * 32 + q * 8];

  // GEMM1': A = W1^T frags, B = z frags. Batched loads per kk-group.
  const f16x8* W1f = (const f16x8*)W1p;
  f32x4 a1[8];
#pragma unroll
  for (int t = 0; t < 8; t++) a1[t] = (f32x4){0.f, 0.f, 0.f, 0.f};
#pragma unroll
  for (int kk = 0; kk < 4; kk++) {
    f16x8 wf[8];
#pragma unroll
    for (int t = 0; t < 8; t++) wf[t] = W1f[(t * 4 + kk) * 64 + lane];
#pragma unroll
    for (int t = 0; t < 8; t++)
      a1[t] = __builtin_amdgcn_mfma_f32_16x16x32_f16(wf[t], zf[kk], a1[t], 0, 0, 0);
  }

  // bias + relu -> fp16, assembled directly into GEMM2 B-frags
  f16x8 tf[4];
#pragma unroll
  for (int t = 0; t < 8; t++) {
    float4 bb = *(const float4*)(b1 + t * 16 + q * 4);
    float bbr[4] = {bb.x, bb.y, bb.z, bb.w};
#pragma unroll
    for (int r = 0; r < 4; r++) {
      float v = fmaxf(a1[t][r] + bbr[r], 0.f);
      tf[t >> 1][(t & 1) * 4 + r] = (_Float16)v;
    }
  }

  // residual loads (fp16) issued here so latency hides under GEMM2's MFMAs
  ushort4 hr4[8];
#pragma unroll
  for (int t = 0; t < 8; t++) hr4[t] = *(const ushort4*)(hb + base + t * 16 + q * 4);

  // GEMM2': A = k-permuted W2^T frags, B = tf. Batched loads.
  const f16x8* W2f = (const f16x8*)W2p;
  f32x4 a2[8];
#pragma unroll
  for (int t = 0; t < 8; t++) a2[t] = (f32x4){0.f, 0.f, 0.f, 0.f};
#pragma unroll
  for (int g = 0; g < 4; g++) {
    f16x8 wf[8];
#pragma unroll
    for (int t = 0; t < 8; t++) wf[t] = W2f[(t * 4 + g) * 64 + lane];
#pragma unroll
    for (int t = 0; t < 8; t++)
      a2[t] = __builtin_amdgcn_mfma_f32_16x16x32_f16(wf[t], tf[g], a2[t], 0, 0, 0);
  }

  // epilogue (per-node; lane holds dims 16t+4q+r of node)
  float s = 0.f, qs = 0.f;
#pragma unroll
  for (int t = 0; t < 8; t++) {
    float4 bb = *(const float4*)(b2 + t * 16 + q * 4);
    float bbr[4] = {bb.x, bb.y, bb.z, bb.w};
#pragma unroll
    for (int r = 0; r < 4; r++) {
      float u = a2[t][r] + bbr[r];
      a2[t][r] = u;
      s += u;
      qs += u * u;
    }
  }
  s += __shfl_xor(s, 16, 64);
  s += __shfl_xor(s, 32, 64);
  qs += __shfl_xor(qs, 16, 64);
  qs += __shfl_xor(qs, 32, 64);
  float mean = s * (1.0f / DD);
  float var = qs * (1.0f / DD) - mean * mean;
  float rstd = rsqrtf(var + LN_EPS);

  if (!LAST) {
#pragma unroll
    for (int t = 0; t < 8; t++) {
      float4 gg4 = *(const float4*)(lng + t * 16 + q * 4);
      float4 nb4 = *(const float4*)(lnb + t * 16 + q * 4);
      float ggr[4] = {gg4.x, gg4.y, gg4.z, gg4.w};
      float nbr[4] = {nb4.x, nb4.y, nb4.z, nb4.w};
      float hr[4] = {h2f(hr4[t].x), h2f(hr4[t].y), h2f(hr4[t].z), h2f(hr4[t].w)};
      float o[4];
#pragma unroll
      for (int r = 0; r < 4; r++) {
        float zz = (a2[t][r] - mean) * rstd * ggr[r] + nbr[r];
        o[r] = gelu_fast(zz) + hr[r];
      }
      if (valid) {
        ushort4 us;
        us.x = f2h(o[0]);
        us.y = f2h(o[1]);
        us.z = f2h(o[2]);
        us.w = f2h(o[3]);
        *(ushort4*)(hbout + base + t * 16 + q * 4) = us;
      }
    }
  } else {
    // hsum = (h1 + h2) + h3 in registers -> final pre-LN -> fp16 zo
    float w[8][4];
    float s2 = 0.f, q2 = 0.f;
#pragma unroll
    for (int t = 0; t < 8; t++) {
      float4 gg4 = *(const float4*)(lng + t * 16 + q * 4);
      float4 nb4 = *(const float4*)(lnb + t * 16 + q * 4);
      ushort4 hp4 = *(const ushort4*)(hbprev1 + base + t * 16 + q * 4);
      float ggr[4] = {gg4.x, gg4.y, gg4.z, gg4.w};
      float nbr[4] = {nb4.x, nb4.y, nb4.z, nb4.w};
      float hr[4] = {h2f(hr4[t].x), h2f(hr4[t].y), h2f(hr4[t].z), h2f(hr4[t].w)};
      float pr[4] = {h2f(hp4.x), h2f(hp4.y), h2f(hp4.z), h2f(hp4.w)};
#pragma unroll
      for (int r = 0; r < 4; r++) {
        float zz = (a2[t][r] - mean) * rstd * ggr[r] + nbr[r];
        float o = gelu_fast(zz) + hr[r];  // h3
        float wv = (pr[r] + hr[r]) + o;
        w[t][r] = wv;
        s2 += wv;
        q2 += wv * wv;
      }
    }
    s2 += __shfl_xor(s2, 16, 64);
    s2 += __shfl_xor(s2, 32, 64);
    q2 += __shfl_xor(q2, 16, 64);
    q2 += __shfl_xor(q2, 32, 64);
    float mean2 = s2 * (1.0f / DD);
    float var2 = q2 * (1.0f / DD) - mean2 * mean2;
    float rstd2 = rsqrtf(var2 + LN_EPS);
#pragma unroll
    for (int t = 0; t < 8; t++) {
      float4 pg4 = *(const float4*)(pg + t * 16 + q * 4);
      float4 pb4 = *(const float4*)(pbv + t * 16 + q * 4);
      float pgr[4] = {pg4.x, pg4.y, pg4.z, pg4.w};
      float pbr[4] = {pb4.x, pb4.y, pb4.z, pb4.w};
      float v0 = (w[t][0] - mean2) * rstd2 * pgr[0] + pbr[0];
      float v1 = (w[t][1] - mean2) * rstd2 * pgr[1] + pbr[1];
      float v2 = (w[t][2] - mean2) * rstd2 * pgr[2] + pbr[2];
      float v3 = (w[t][3] - mean2) * rstd2 * pgr[3] + pbr[3];
      if (valid) {
        ushort4 us;
        us.x = f2h(v0);
        us.y = f2h(v1);
        us.z = f2h(v2);
        us.w = f2h(v3);
        *(ushort4*)(zo + base + t * 16 + q * 4) = us;
      }
    }
  }
}

// ---------------- final GEMM: out = A*pW + pb, fp16 single-MFMA --------------
__global__ __launch_bounds__(256, 4) void k_mm(const ushort_t* __restrict__ zo,
                                               const ushort_t* __restrict__ Bp,
                                               const float* __restrict__ bias,
                                               float* __restrict__ out) {
  int lane = threadIdx.x & 63;
  int wid = threadIdx.x >> 6;
  int m = lane & 15;
  int q = lane >> 4;
  int node = blockIdx.x * 64 + wid * 16 + m;
  int valid = node < NN;
  int node_c = valid ? node : (NN - 1);
  size_t base = (size_t)node_c * DD;
  const f16x8* Zf = (const f16x8*)(zo + base);
  f16x8 zf[4];
#pragma unroll
  for (int kk = 0; kk < 4; kk++) zf[kk] = Zf[kk * 4 + q];
  const f16x8* Bf = (const f16x8*)Bp;
  f32x4 acc[8];
#pragma unroll
  for (int t = 0; t < 8; t++) acc[t] = (f32x4){0.f, 0.f, 0.f, 0.f};
#pragma unroll
  for (int kk = 0; kk < 4; kk++) {
    f16x8 wf[8];
#pragma unroll
    for (int t = 0; t < 8; t++) wf[t] = Bf[(t * 4 + kk) * 64 + lane];
#pragma unroll
    for (int t = 0; t < 8; t++)
      acc[t] = __builtin_amdgcn_mfma_f32_16x16x32_f16(wf[t], zf[kk], acc[t], 0, 0, 0);
  }
  if (valid) {
#pragma unroll
    for (int t = 0; t < 8; t++) {
      float4 bb = *(const float4*)(bias + t * 16 + q * 4);
      float4 o4;
      o4.x = acc[t][0] + bb.x;
      o4.y = acc[t][1] + bb.y;
      o4.z = acc[t][2] + bb.z;
      o4.w = acc[t][3] + bb.w;
      *(float4*)(out + base + t * 16 + q * 4) = o4;
    }
  }
}

extern "C" void kernel_launch(void* const* d_in, const int* in_sizes, int n_in, void* d_out,
                              int out_size, void* d_ws, size_t ws_size, hipStream_t stream) {
  (void)in_sizes;
  (void)n_in;
  (void)out_size;
  (void)ws_size;
  const float* x = (const float*)d_in[0];
  const int* ei = (const int*)d_in[1];
  const float* W1 = (const float*)d_in[2];
  const float* b1 = (const float*)d_in[3];
  const float* W2 = (const float*)d_in[4];
  const float* b2 = (const float*)d_in[5];
  const float* eps = (const float*)d_in[6];
  const float* lng = (const float*)d_in[7];
  const float* lnb = (const float*)d_in[8];
  const float* plg = (const float*)d_in[9];
  const float* plb = (const float*)d_in[10];
  const float* pW = (const float*)d_in[11];
  const float* pb = (const float*)d_in[12];
  float* out = (float*)d_out;

  char* ws = (char*)d_ws;
  ushort_t* hb0 = (ushort_t*)ws;
  ws += (size_t)NN * DD * 2;
  ushort_t* hb1 = (ushort_t*)ws;
  ws += (size_t)NN * DD * 2;
  ushort_t* hb2 = (ushort_t*)ws;
  ws += (size_t)NN * DD * 2;
  ushort_t* zo = (ushort_t*)ws;
  ws += (size_t)NN * DD * 2;
  ushort_t* wp = (ushort_t*)ws;
  ws += (size_t)7 * 16384 * 2;
  int* deg = (int*)ws;
  ws += (size_t)NN * 4;
  int* rowst = (int*)ws;
  ws += (size_t)(NN + 1) * 4 + 60;
  int* bsum = (int*)ws;
  ws += 512;
  int* csr = (int*)ws;
  ws += (size_t)NE * 4;
  int* epos = (int*)ws;
  ws += (size_t)NE * 4;

  const int* srcv = ei;
  const int* dstv = ei + NE;

  hipMemsetAsync(deg, 0, (size_t)NN * 4, stream);
  k_count<<<(NE + 255) / 256, 256, 0, stream>>>(dstv, deg, epos);
  k_block_sums<<<98, 256, 0, stream>>>(deg, bsum);
  k_scan_sums<<<1, 128, 0, stream>>>(bsum, 98);
  k_scan_write<<<98, 256, 0, stream>>>(deg, bsum, rowst);
  k_fill<<<4096, 256, 0, stream>>>(srcv, dstv, rowst, epos, csr);
  k_pack<<<448, 256, 0, stream>>>(W1, W2, pW, wp);
  k_cast<<<(NN * DD / 4 + 255) / 256, 256, 0, stream>>>(x, hb0);

  int mlp_grid = (NN + 63) / 64;  // 1563, 4 waves/block, 16 nodes/wave
  ushort_t* hbs[NL + 1] = {hb0, hb1, hb2, nullptr};
  for (int l = 0; l < NL; l++) {
    if (l < NL - 1) {
      k_gmlp<0><<<mlp_grid, 256, 0, stream>>>(
          hbs[l], rowst, csr, eps, l, wp + (size_t)(2 * l) * 16384,
          wp + (size_t)(2 * l + 1) * 16384, b1 + l * DD, b2 + l * DD, lng + l * DD,
          lnb + l * DD, hb1, hbs[l + 1], plg, plb, zo);
    } else {
      k_gmlp<1><<<mlp_grid, 256, 0, stream>>>(
          hbs[l], rowst, csr, eps, l, wp + (size_t)(2 * l) * 16384,
          wp + (size_t)(2 * l + 1) * 16384, b1 + l * DD, b2 + l * DD, lng + l * DD,
          lnb + l * DD, hb1, nullptr, plg, plb, zo);
    }
  }
  k_mm<<<mlp_grid, 256, 0, stream>>>(zo, wp + (size_t)6 * 16384, pb, out);
}

// Round 13
// 573.499 us; speedup vs baseline: 1.1682x; 1.1682x over previous
//
#include <hip/hip_runtime.h>
#include <math.h>

#define NN 100000
#define NE 1600000
#define DD 128
#define NL 3
#define LN_EPS 1e-5f
#define NRANGE 8
#define RSZ (NN / NRANGE)  // 12500

typedef __attribute__((ext_vector_type(8))) _Float16 f16x8;
typedef __attribute__((ext_vector_type(4))) float f32x4;
typedef unsigned short ushort_t;

__device__ __forceinline__ unsigned short f2h(float f) {
  _Float16 h = (_Float16)f;
  unsigned short u;
  __builtin_memcpy(&u, &h, 2);
  return u;
}
__device__ __forceinline__ float h2f(unsigned short u) {
  _Float16 h;
  __builtin_memcpy(&h, &u, 2);
  return (float)h;
}
// gelu with fast erf (A&S 7.1.26, |err|<1.5e-7 -- far below tolerance)
__device__ __forceinline__ float gelu_fast(float x) {
  float xs = x * 0.7071067811865476f;
  float ax = fabsf(xs);
  float t = __builtin_amdgcn_rcpf(fmaf(0.3275911f, ax, 1.0f));
  float p = fmaf(t, 1.061405429f, -1.453152027f);
  p = fmaf(t, p, 1.421413741f);
  p = fmaf(t, p, -0.284496736f);
  p = fmaf(t, p, 0.254829592f);
  p = p * t;
  float e = __expf(-ax * ax);
  float er = fmaf(-p, e, 1.0f);
  er = copysignf(er, xs);
  return 0.5f * x * (1.0f + er);
}

// ---------------- CSR build ----------------
// ONE atomic pass: k_count records each edge's slot (epos). k_fill then has
// ZERO atomics and stays XCD-ranged so scatter stores merge in the local L2.
__global__ __launch_bounds__(256) void k_count(const int* __restrict__ dst,
                                               int* __restrict__ deg,
                                               int* __restrict__ epos) {
  int e = blockIdx.x * blockDim.x + threadIdx.x;
  if (e < NE) epos[e] = atomicAdd(&deg[dst[e]], 1);
}

__global__ void k_block_sums(const int* __restrict__ deg, int* __restrict__ bsum) {
  __shared__ int sh[256];
  int t = threadIdx.x;
  int base = blockIdx.x * 1024;
  int s = 0;
#pragma unroll
  for (int j = 0; j < 4; j++) {
    int idx = base + t * 4 + j;
    if (idx < NN) s += deg[idx];
  }
  sh[t] = s;
  __syncthreads();
  for (int off = 128; off > 0; off >>= 1) {
    if (t < off) sh[t] += sh[t + off];
    __syncthreads();
  }
  if (t == 0) bsum[blockIdx.x] = sh[0];
}

__global__ void k_scan_sums(int* __restrict__ bsum, int nb) {
  __shared__ int sh[128];
  int t = threadIdx.x;
  int v = (t < nb) ? bsum[t] : 0;
  int acc = v;
  sh[t] = v;
  __syncthreads();
  for (int off = 1; off < 128; off <<= 1) {
    int o = (t >= off) ? sh[t - off] : 0;
    __syncthreads();
    acc += o;
    sh[t] = acc;
    __syncthreads();
  }
  if (t < nb) bsum[t] = acc - v;  // exclusive
}

__global__ void k_scan_write(const int* __restrict__ deg, const int* __restrict__ bsum,
                             int* __restrict__ rowstart) {
  __shared__ int sh[256];
  int t = threadIdx.x;
  int base = blockIdx.x * 1024;
  int idx0 = base + t * 4;
  int v[4];
  int s = 0;
#pragma unroll
  for (int j = 0; j < 4; j++) {
    int idx = idx0 + j;
    v[j] = (idx < NN) ? deg[idx] : 0;
    s += v[j];
  }
  int acc = s;
  sh[t] = s;
  __syncthreads();
  for (int off = 1; off < 256; off <<= 1) {
    int o = (t >= off) ? sh[t - off] : 0;
    __syncthreads();
    acc += o;
    sh[t] = acc;
    __syncthreads();
  }
  int excl = acc - s + bsum[blockIdx.x];
#pragma unroll
  for (int j = 0; j < 4; j++) {
    int idx = idx0 + j;
    if (idx < NN) rowstart[idx] = excl;
    excl += v[j];
  }
  if (blockIdx.x == 0 && t == 0) rowstart[NN] = NE;
}

__global__ __launch_bounds__(256) void k_fill(const int* __restrict__ src,
                                              const int* __restrict__ dst,
                                              const int* __restrict__ rowstart,
                                              const int* __restrict__ epos,
                                              int* __restrict__ csr) {
  int range = blockIdx.x & (NRANGE - 1);
  int lo = range * RSZ;
  int hi = lo + RSZ;
  int nblk = gridDim.x >> 3;
  int bid = blockIdx.x >> 3;
  for (int e = bid * 256 + threadIdx.x; e < NE; e += nblk * 256) {
    int d = dst[e];
    if (d >= lo && d < hi) {
      csr[rowstart[d] + epos[e]] = src[e];
    }
  }
}

// ---------------- W pre-pack into MFMA A-of-W^T fragment order (fp16) --------
// W1, pW: k = 32kk + 8q + j (natural order).
// W2:     k = 32kk + 16(j>>2) + 4q + (j&3) -- permutation that makes the
//         GEMM2 B-fragment equal the GEMM1' accumulator layout (no LDS xpose).
__global__ void k_pack(const float* __restrict__ W1, const float* __restrict__ W2,
                       const float* __restrict__ pW, ushort_t* __restrict__ wp) {
  int id = blockIdx.x * 256 + threadIdx.x;  // 7*16384
  int mtx = id >> 14;                       // 0..6
  int r = id & 16383;
  const float* src;
  int perm = 0;
  if (mtx == 6) {
    src = pW;  // natural pack: k_mm consumes memory-layout B-frags
  } else {
    int layer = mtx >> 1;
    if (mtx & 1) {
      src = W2 + layer * 16384;
      perm = 1;
    } else {
      src = W1 + layer * 16384;
    }
  }
  int j = r & 7;
  int l = (r >> 3) & 63;
  int kk = (r >> 9) & 3;
  int t = r >> 11;
  int qq = (l >> 4) & 3;
  int k = perm ? (kk * 32 + ((j >> 2) << 4) + (qq << 2) + (j & 3))
               : (kk * 32 + (qq << 3) + j);
  int n = t * 16 + (l & 15);
  wp[id] = f2h(src[k * DD + n]);
}

// ---------------- x -> fp16 h0 ----------------
__global__ void k_cast(const float* __restrict__ x, ushort_t* __restrict__ hb) {
  int i = blockIdx.x * 256 + threadIdx.x;  // over NN*DD/4
  if (i < NN * DD / 4) {
    float4 v = ((const float4*)x)[i];
    ushort4 o;
    o.x = f2h(v.x);
    o.y = f2h(v.y);
    o.z = f2h(v.z);
    o.w = f2h(v.w);
    ((ushort4*)hb)[i] = o;
  }
}

// ---- gather: z = (1+eps)*hb[n] + sum_{incoming} hb[src] (fp16) -> fp16 z ----
// Quarter-wave edge streams: 16 lanes per row (uint4 = 16B/lane), 4 streams
// per wave (k = s+g, s+g+4, ...), 4-deep unroll -> 16 independent row-loads
// (4KB) in flight per wave, one VMEM instruction per 4 edges. Merge via
// shfl_xor 16 + 32; z layout byte-identical to the MFMA B-fragment order.
__global__ __launch_bounds__(256) void k_gather(const ushort_t* __restrict__ hb,
                                                const int* __restrict__ rowstart,
                                                const int* __restrict__ csr,
                                                const float* __restrict__ eps, int layer,
                                                uint4* __restrict__ z) {
  int n = blockIdx.x * 4 + (threadIdx.x >> 6);
  int lane = threadIdx.x & 63;
  int g = lane >> 4;   // quarter-wave edge-stream id (0..3)
  int ii = lane & 15;  // uint4 index within the 256B row
  const uint4* hb4 = (const uint4*)hb;

  float a[8] = {0.f, 0.f, 0.f, 0.f, 0.f, 0.f, 0.f, 0.f};
  if (g == 0) {
    uint4 v = hb4[(size_t)n * 16 + ii];
    float e1 = 1.0f + eps[layer];
    a[0] = e1 * h2f((ushort_t)(v.x & 0xffffu));
    a[1] = e1 * h2f((ushort_t)(v.x >> 16));
    a[2] = e1 * h2f((ushort_t)(v.y & 0xffffu));
    a[3] = e1 * h2f((ushort_t)(v.y >> 16));
    a[4] = e1 * h2f((ushort_t)(v.z & 0xffffu));
    a[5] = e1 * h2f((ushort_t)(v.z >> 16));
    a[6] = e1 * h2f((ushort_t)(v.w & 0xffffu));
    a[7] = e1 * h2f((ushort_t)(v.w >> 16));
  }
  float b[8] = {0.f, 0.f, 0.f, 0.f, 0.f, 0.f, 0.f, 0.f};
  float c[8] = {0.f, 0.f, 0.f, 0.f, 0.f, 0.f, 0.f, 0.f};
  float d[8] = {0.f, 0.f, 0.f, 0.f, 0.f, 0.f, 0.f, 0.f};

  int s = rowstart[n], e = rowstart[n + 1];
  int k = s + g;
  for (; k + 12 < e; k += 16) {  // this stream: edges k, k+4, k+8, k+12
    int i0 = csr[k], i1 = csr[k + 4], i2 = csr[k + 8], i3 = csr[k + 12];
    uint4 v0 = hb4[(size_t)i0 * 16 + ii];
    uint4 v1 = hb4[(size_t)i1 * 16 + ii];
    uint4 v2 = hb4[(size_t)i2 * 16 + ii];
    uint4 v3 = hb4[(size_t)i3 * 16 + ii];
    a[0] += h2f((ushort_t)(v0.x & 0xffffu));
    a[1] += h2f((ushort_t)(v0.x >> 16));
    a[2] += h2f((ushort_t)(v0.y & 0xffffu));
    a[3] += h2f((ushort_t)(v0.y >> 16));
    a[4] += h2f((ushort_t)(v0.z & 0xffffu));
    a[5] += h2f((ushort_t)(v0.z >> 16));
    a[6] += h2f((ushort_t)(v0.w & 0xffffu));
    a[7] += h2f((ushort_t)(v0.w >> 16));
    b[0] += h2f((ushort_t)(v1.x & 0xffffu));
    b[1] += h2f((ushort_t)(v1.x >> 16));
    b[2] += h2f((ushort_t)(v1.y & 0xffffu));
    b[3] += h2f((ushort_t)(v1.y >> 16));
    b[4] += h2f((ushort_t)(v1.z & 0xffffu));
    b[5] += h2f((ushort_t)(v1.z >> 16));
    b[6] += h2f((ushort_t)(v1.w & 0xffffu));
    b[7] += h2f((ushort_t)(v1.w >> 16));
    c[0] += h2f((ushort_t)(v2.x & 0xffffu));
    c[1] += h2f((ushort_t)(v2.x >> 16));
    c[2] += h2f((ushort_t)(v2.y & 0xffffu));
    c[3] += h2f((ushort_t)(v2.y >> 16));
    c[4] += h2f((ushort_t)(v2.z & 0xffffu));
    c[5] += h2f((ushort_t)(v2.z >> 16));
    c[6] += h2f((ushort_t)(v2.w & 0xffffu));
    c[7] += h2f((ushort_t)(v2.w >> 16));
    d[0] += h2f((ushort_t)(v3.x & 0xffffu));
    d[1] += h2f((ushort_t)(v3.x >> 16));
    d[2] += h2f((ushort_t)(v3.y & 0xffffu));
    d[3] += h2f((ushort_t)(v3.y >> 16));
    d[4] += h2f((ushort_t)(v3.z & 0xffffu));
    d[5] += h2f((ushort_t)(v3.z >> 16));
    d[6] += h2f((ushort_t)(v3.w & 0xffffu));
    d[7] += h2f((ushort_t)(v3.w >> 16));
  }
  for (; k < e; k += 4) {
    uint4 v = hb4[(size_t)csr[k] * 16 + ii];
    a[0] += h2f((ushort_t)(v.x & 0xffffu));
    a[1] += h2f((ushort_t)(v.x >> 16));
    a[2] += h2f((ushort_t)(v.y & 0xffffu));
    a[3] += h2f((ushort_t)(v.y >> 16));
    a[4] += h2f((ushort_t)(v.z & 0xffffu));
    a[5] += h2f((ushort_t)(v.z >> 16));
    a[6] += h2f((ushort_t)(v.w & 0xffffu));
    a[7] += h2f((ushort_t)(v.w >> 16));
  }
#pragma unroll
  for (int j = 0; j < 8; j++) {
    a[j] += (b[j] + c[j]) + d[j];
    a[j] += __shfl_xor(a[j], 16, 64);
    a[j] += __shfl_xor(a[j], 32, 64);
  }
  if (g == 0) {
    uint4 o;
    o.x = (unsigned)f2h(a[0]) | ((unsigned)f2h(a[1]) << 16);
    o.y = (unsigned)f2h(a[2]) | ((unsigned)f2h(a[3]) << 16);
    o.z = (unsigned)f2h(a[4]) | ((unsigned)f2h(a[5]) << 16);
    o.w = (unsigned)f2h(a[6]) | ((unsigned)f2h(a[7]) << 16);
    z[(size_t)n * 16 + ii] = o;
  }
}

// ------- fused MLP: swapped-operand, LDS-free, fp16 single-MFMA --------------
template <int LAST>
__global__ __launch_bounds__(256, 4) void k_mlp(
    const ushort_t* __restrict__ z, const ushort_t* __restrict__ W1p,
    const ushort_t* __restrict__ W2p, const float* __restrict__ b1,
    const float* __restrict__ b2, const float* __restrict__ lng,
    const float* __restrict__ lnb, const ushort_t* __restrict__ hbin,
    const ushort_t* __restrict__ hbprev1, ushort_t* __restrict__ hbout,
    const float* __restrict__ pg, const float* __restrict__ pbv,
    ushort_t* __restrict__ zo) {
  int lane = threadIdx.x & 63;
  int wid = threadIdx.x >> 6;
  int m = lane & 15;
  int q = lane >> 4;
  int node = blockIdx.x * 64 + wid * 16 + m;
  int valid = node < NN;
  int node_c = valid ? node : (NN - 1);
  size_t base = (size_t)node_c * DD;

  // z fragments (B-operand of GEMM1'), 4 k-groups
  const f16x8* Zf = (const f16x8*)(z + base);
  f16x8 zf[4];
#pragma unroll
  for (int kk = 0; kk < 4; kk++) zf[kk] = Zf[kk * 4 + q];

  // ---- GEMM1': A = W1^T frags, B = z frags. Batched loads per kk-group.
  const f16x8* W1f = (const f16x8*)W1p;
  f32x4 a1[8];
#pragma unroll
  for (int t = 0; t < 8; t++) a1[t] = (f32x4){0.f, 0.f, 0.f, 0.f};
#pragma unroll
  for (int kk = 0; kk < 4; kk++) {
    f16x8 wf[8];
#pragma unroll
    for (int t = 0; t < 8; t++) wf[t] = W1f[(t * 4 + kk) * 64 + lane];
#pragma unroll
    for (int t = 0; t < 8; t++)
      a1[t] = __builtin_amdgcn_mfma_f32_16x16x32_f16(wf[t], zf[kk], a1[t], 0, 0, 0);
  }

  // ---- bias + relu -> fp16, assembled directly into GEMM2 B-frags
  f16x8 tf[4];
#pragma unroll
  for (int t = 0; t < 8; t++) {
    float4 bb = *(const float4*)(b1 + t * 16 + q * 4);
    float bbr[4] = {bb.x, bb.y, bb.z, bb.w};
#pragma unroll
    for (int r = 0; r < 4; r++) {
      float v = fmaxf(a1[t][r] + bbr[r], 0.f);
      tf[t >> 1][(t & 1) * 4 + r] = (_Float16)v;
    }
  }

  // residual loads (fp16) issued here so latency hides under GEMM2's MFMAs
  ushort4 hr4[8];
#pragma unroll
  for (int t = 0; t < 8; t++) hr4[t] = *(const ushort4*)(hbin + base + t * 16 + q * 4);

  // ---- GEMM2': A = k-permuted W2^T frags, B = tf. Batched loads.
  const f16x8* W2f = (const f16x8*)W2p;
  f32x4 a2[8];
#pragma unroll
  for (int t = 0; t < 8; t++) a2[t] = (f32x4){0.f, 0.f, 0.f, 0.f};
#pragma unroll
  for (int g = 0; g < 4; g++) {
    f16x8 wf[8];
#pragma unroll
    for (int t = 0; t < 8; t++) wf[t] = W2f[(t * 4 + g) * 64 + lane];
#pragma unroll
    for (int t = 0; t < 8; t++)
      a2[t] = __builtin_amdgcn_mfma_f32_16x16x32_f16(wf[t], tf[g], a2[t], 0, 0, 0);
  }

  // ---- epilogue (per-node; lane holds dims 16t+4q+r of node)
  float s = 0.f, qs = 0.f;
#pragma unroll
  for (int t = 0; t < 8; t++) {
    float4 bb = *(const float4*)(b2 + t * 16 + q * 4);
    float bbr[4] = {bb.x, bb.y, bb.z, bb.w};
#pragma unroll
    for (int r = 0; r < 4; r++) {
      float u = a2[t][r] + bbr[r];
      a2[t][r] = u;
      s += u;
      qs += u * u;
    }
  }
  s += __shfl_xor(s, 16, 64);
  s += __shfl_xor(s, 32, 64);
  qs += __shfl_xor(qs, 16, 64);
  qs += __shfl_xor(qs, 32, 64);
  float mean = s * (1.0f / DD);
  float var = qs * (1.0f / DD) - mean * mean;
  float rstd = rsqrtf(var + LN_EPS);

  if (!LAST) {
#pragma unroll
    for (int t = 0; t < 8; t++) {
      float4 gg4 = *(const float4*)(lng + t * 16 + q * 4);
      float4 nb4 = *(const float4*)(lnb + t * 16 + q * 4);
      float ggr[4] = {gg4.x, gg4.y, gg4.z, gg4.w};
      float nbr[4] = {nb4.x, nb4.y, nb4.z, nb4.w};
      float hr[4] = {h2f(hr4[t].x), h2f(hr4[t].y), h2f(hr4[t].z), h2f(hr4[t].w)};
      float o[4];
#pragma unroll
      for (int r = 0; r < 4; r++) {
        float zz = (a2[t][r] - mean) * rstd * ggr[r] + nbr[r];
        o[r] = gelu_fast(zz) + hr[r];
      }
      if (valid) {
        ushort4 us;
        us.x = f2h(o[0]);
        us.y = f2h(o[1]);
        us.z = f2h(o[2]);
        us.w = f2h(o[3]);
        *(ushort4*)(hbout + base + t * 16 + q * 4) = us;
      }
    }
  } else {
    // hsum = (h1 + h2) + h3 in registers -> final pre-LN -> fp16 zo
    float w[8][4];
    float s2 = 0.f, q2 = 0.f;
#pragma unroll
    for (int t = 0; t < 8; t++) {
      float4 gg4 = *(const float4*)(lng + t * 16 + q * 4);
      float4 nb4 = *(const float4*)(lnb + t * 16 + q * 4);
      ushort4 hp4 = *(const ushort4*)(hbprev1 + base + t * 16 + q * 4);
      float ggr[4] = {gg4.x, gg4.y, gg4.z, gg4.w};
      float nbr[4] = {nb4.x, nb4.y, nb4.z, nb4.w};
      float hr[4] = {h2f(hr4[t].x), h2f(hr4[t].y), h2f(hr4[t].z), h2f(hr4[t].w)};
      float pr[4] = {h2f(hp4.x), h2f(hp4.y), h2f(hp4.z), h2f(hp4.w)};
#pragma unroll
      for (int r = 0; r < 4; r++) {
        float zz = (a2[t][r] - mean) * rstd * ggr[r] + nbr[r];
        float o = gelu_fast(zz) + hr[r];  // h3
        float wv = (pr[r] + hr[r]) + o;
        w[t][r] = wv;
        s2 += wv;
        q2 += wv * wv;
      }
    }
    s2 += __shfl_xor(s2, 16, 64);
    s2 += __shfl_xor(s2, 32, 64);
    q2 += __shfl_xor(q2, 16, 64);
    q2 += __shfl_xor(q2, 32, 64);
    float mean2 = s2 * (1.0f / DD);
    float var2 = q2 * (1.0f / DD) - mean2 * mean2;
    float rstd2 = rsqrtf(var2 + LN_EPS);
#pragma unroll
    for (int t = 0; t < 8; t++) {
      float4 pg4 = *(const float4*)(pg + t * 16 + q * 4);
      float4 pb4 = *(const float4*)(pbv + t * 16 + q * 4);
      float pgr[4] = {pg4.x, pg4.y, pg4.z, pg4.w};
      float pbr[4] = {pb4.x, pb4.y, pb4.z, pb4.w};
      float v0 = (w[t][0] - mean2) * rstd2 * pgr[0] + pbr[0];
      float v1 = (w[t][1] - mean2) * rstd2 * pgr[1] + pbr[1];
      float v2 = (w[t][2] - mean2) * rstd2 * pgr[2] + pbr[2];
      float v3 = (w[t][3] - mean2) * rstd2 * pgr[3] + pbr[3];
      if (valid) {
        ushort4 us;
        us.x = f2h(v0);
        us.y = f2h(v1);
        us.z = f2h(v2);
        us.w = f2h(v3);
        *(ushort4*)(zo + base + t * 16 + q * 4) = us;
      }
    }
  }
}

// ---------------- final GEMM: out = A*pW + pb, fp16 single-MFMA --------------
__global__ __launch_bounds__(256, 4) void k_mm(const ushort_t* __restrict__ zo,
                                               const ushort_t* __restrict__ Bp,
                                               const float* __restrict__ bias,
                                               float* __restrict__ out) {
  int lane = threadIdx.x & 63;
  int wid = threadIdx.x >> 6;
  int m = lane & 15;
  int q = lane >> 4;
  int node = blockIdx.x * 64 + wid * 16 + m;
  int valid = node < NN;
  int node_c = valid ? node : (NN - 1);
  size_t base = (size_t)node_c * DD;
  const f16x8* Zf = (const f16x8*)(zo + base);
  f16x8 zf[4];
#pragma unroll
  for (int kk = 0; kk < 4; kk++) zf[kk] = Zf[kk * 4 + q];
  const f16x8* Bf = (const f16x8*)Bp;
  f32x4 acc[8];
#pragma unroll
  for (int t = 0; t < 8; t++) acc[t] = (f32x4){0.f, 0.f, 0.f, 0.f};
#pragma unroll
  for (int kk = 0; kk < 4; kk++) {
    f16x8 wf[8];
#pragma unroll
    for (int t = 0; t < 8; t++) wf[t] = Bf[(t * 4 + kk) * 64 + lane];
#pragma unroll
    for (int t = 0; t < 8; t++)
      acc[t] = __builtin_amdgcn_mfma_f32_16x16x32_f16(wf[t], zf[kk], acc[t], 0, 0, 0);
  }
  if (valid) {
#pragma unroll
    for (int t = 0; t < 8; t++) {
      float4 bb = *(const float4*)(bias + t * 16 + q * 4);
      float4 o4;
      o4.x = acc[t][0] + bb.x;
      o4.y = acc[t][1] + bb.y;
      o4.z = acc[t][2] + bb.z;
      o4.w = acc[t][3] + bb.w;
      *(float4*)(out + base + t * 16 + q * 4) = o4;
    }
  }
}

extern "C" void kernel_launch(void* const* d_in, const int* in_sizes, int n_in, void* d_out,
                              int out_size, void* d_ws, size_t ws_size, hipStream_t stream) {
  (void)in_sizes;
  (void)n_in;
  (void)out_size;
  (void)ws_size;
  const float* x = (const float*)d_in[0];
  const int* ei = (const int*)d_in[1];
  const float* W1 = (const float*)d_in[2];
  const float* b1 = (const float*)d_in[3];
  const float* W2 = (const float*)d_in[4];
  const float* b2 = (const float*)d_in[5];
  const float* eps = (const float*)d_in[6];
  const float* lng = (const float*)d_in[7];
  const float* lnb = (const float*)d_in[8];
  const float* plg = (const float*)d_in[9];
  const float* plb = (const float*)d_in[10];
  const float* pW = (const float*)d_in[11];
  const float* pb = (const float*)d_in[12];
  float* out = (float*)d_out;

  char* ws = (char*)d_ws;
  ushort_t* hb0 = (ushort_t*)ws;
  ws += (size_t)NN * DD * 2;
  ushort_t* hb1 = (ushort_t*)ws;
  ws += (size_t)NN * DD * 2;
  ushort_t* hb2 = (ushort_t*)ws;
  ws += (size_t)NN * DD * 2;
  ushort_t* z = (ushort_t*)ws;
  ws += (size_t)NN * DD * 2;
  ushort_t* zo = (ushort_t*)ws;
  ws += (size_t)NN * DD * 2;
  ushort_t* wp = (ushort_t*)ws;
  ws += (size_t)7 * 16384 * 2;
  int* deg = (int*)ws;
  ws += (size_t)NN * 4;
  int* rowst = (int*)ws;
  ws += (size_t)(NN + 1) * 4 + 60;
  int* bsum = (int*)ws;
  ws += 512;
  int* csr = (int*)ws;
  ws += (size_t)NE * 4;
  int* epos = (int*)ws;
  ws += (size_t)NE * 4;

  const int* srcv = ei;
  const int* dstv = ei + NE;

  hipMemsetAsync(deg, 0, (size_t)NN * 4, stream);
  k_count<<<(NE + 255) / 256, 256, 0, stream>>>(dstv, deg, epos);
  k_block_sums<<<98, 256, 0, stream>>>(deg, bsum);
  k_scan_sums<<<1, 128, 0, stream>>>(bsum, 98);
  k_scan_write<<<98, 256, 0, stream>>>(deg, bsum, rowst);
  k_fill<<<4096, 256, 0, stream>>>(srcv, dstv, rowst, epos, csr);
  k_pack<<<448, 256, 0, stream>>>(W1, W2, pW, wp);
  k_cast<<<(NN * DD / 4 + 255) / 256, 256, 0, stream>>>(x, hb0);

  int mlp_grid = (NN + 63) / 64;  // 1563, 4 waves/block, 16 nodes/wave
  ushort_t* hbs[NL + 1] = {hb0, hb1, hb2, nullptr};
  for (int l = 0; l < NL; l++) {
    k_gather<<<NN / 4, 256, 0, stream>>>(hbs[l], rowst, csr, eps, l, (uint4*)z);
    if (l < NL - 1) {
      k_mlp<0><<<mlp_grid, 256, 0, stream>>>(
          z, wp + (size_t)(2 * l) * 16384, wp + (size_t)(2 * l + 1) * 16384, b1 + l * DD,
          b2 + l * DD, lng + l * DD, lnb + l * DD, hbs[l], hb1, hbs[l + 1], plg, plb, zo);
    } else {
      k_mlp<1><<<mlp_grid, 256, 0, stream>>>(
          z, wp + (size_t)(2 * l) * 16384, wp + (size_t)(2 * l + 1) * 16384, b1 + l * DD,
          b2 + l * DD, lng + l * DD, lnb + l * DD, hbs[l], hb1, hb0, plg, plb, zo);
    }
  }
  k_mm<<<mlp_grid, 256, 0, stream>>>(zo, wp + (size_t)6 * 16384, pb, out);
}

// Round 14
// 565.086 us; speedup vs baseline: 1.1856x; 1.0149x over previous
//
#include <hip/hip_runtime.h>
#include <math.h>

#define NN 100000
#define NE 1600000
#define DD 128
#define NL 3
#define LN_EPS 1e-5f
#define NRANGE 8
#define RSZ (NN / NRANGE)  // 12500

typedef __attribute__((ext_vector_type(8))) _Float16 f16x8;
typedef __attribute__((ext_vector_type(2))) _Float16 f16x2;
typedef __attribute__((ext_vector_type(4))) float f32x4;
typedef unsigned short ushort_t;

__device__ __forceinline__ unsigned short f2h(float f) {
  _Float16 h = (_Float16)f;
  unsigned short u;
  __builtin_memcpy(&u, &h, 2);
  return u;
}
__device__ __forceinline__ float h2f(unsigned short u) {
  _Float16 h;
  __builtin_memcpy(&h, &u, 2);
  return (float)h;
}
__device__ __forceinline__ f16x2 u2h2(unsigned u) {
  f16x2 h;
  __builtin_memcpy(&h, &u, 4);
  return h;
}
// gelu with fast erf (A&S 7.1.26, |err|<1.5e-7 -- far below tolerance)
__device__ __forceinline__ float gelu_fast(float x) {
  float xs = x * 0.7071067811865476f;
  float ax = fabsf(xs);
  float t = __builtin_amdgcn_rcpf(fmaf(0.3275911f, ax, 1.0f));
  float p = fmaf(t, 1.061405429f, -1.453152027f);
  p = fmaf(t, p, 1.421413741f);
  p = fmaf(t, p, -0.284496736f);
  p = fmaf(t, p, 0.254829592f);
  p = p * t;
  float e = __expf(-ax * ax);
  float er = fmaf(-p, e, 1.0f);
  er = copysignf(er, xs);
  return 0.5f * x * (1.0f + er);
}

// ---------------- CSR build ----------------
// ONE atomic pass: k_count records each edge's slot (epos). k_fill then has
// ZERO atomics and stays XCD-ranged so scatter stores merge in the local L2.
__global__ __launch_bounds__(256) void k_count(const int* __restrict__ dst,
                                               int* __restrict__ deg,
                                               int* __restrict__ epos) {
  int e = blockIdx.x * blockDim.x + threadIdx.x;
  if (e < NE) epos[e] = atomicAdd(&deg[dst[e]], 1);
}

__global__ void k_block_sums(const int* __restrict__ deg, int* __restrict__ bsum) {
  __shared__ int sh[256];
  int t = threadIdx.x;
  int base = blockIdx.x * 1024;
  int s = 0;
#pragma unroll
  for (int j = 0; j < 4; j++) {
    int idx = base + t * 4 + j;
    if (idx < NN) s += deg[idx];
  }
  sh[t] = s;
  __syncthreads();
  for (int off = 128; off > 0; off >>= 1) {
    if (t < off) sh[t] += sh[t + off];
    __syncthreads();
  }
  if (t == 0) bsum[blockIdx.x] = sh[0];
}

__global__ void k_scan_sums(int* __restrict__ bsum, int nb) {
  __shared__ int sh[128];
  int t = threadIdx.x;
  int v = (t < nb) ? bsum[t] : 0;
  int acc = v;
  sh[t] = v;
  __syncthreads();
  for (int off = 1; off < 128; off <<= 1) {
    int o = (t >= off) ? sh[t - off] : 0;
    __syncthreads();
    acc += o;
    sh[t] = acc;
    __syncthreads();
  }
  if (t < nb) bsum[t] = acc - v;  // exclusive
}

__global__ void k_scan_write(const int* __restrict__ deg, const int* __restrict__ bsum,
                             int* __restrict__ rowstart) {
  __shared__ int sh[256];
  int t = threadIdx.x;
  int base = blockIdx.x * 1024;
  int idx0 = base + t * 4;
  int v[4];
  int s = 0;
#pragma unroll
  for (int j = 0; j < 4; j++) {
    int idx = idx0 + j;
    v[j] = (idx < NN) ? deg[idx] : 0;
    s += v[j];
  }
  int acc = s;
  sh[t] = s;
  __syncthreads();
  for (int off = 1; off < 256; off <<= 1) {
    int o = (t >= off) ? sh[t - off] : 0;
    __syncthreads();
    acc += o;
    sh[t] = acc;
    __syncthreads();
  }
  int excl = acc - s + bsum[blockIdx.x];
#pragma unroll
  for (int j = 0; j < 4; j++) {
    int idx = idx0 + j;
    if (idx < NN) rowstart[idx] = excl;
    excl += v[j];
  }
  if (blockIdx.x == 0 && t == 0) rowstart[NN] = NE;
}

__global__ __launch_bounds__(256) void k_fill(const int* __restrict__ src,
                                              const int* __restrict__ dst,
                                              const int* __restrict__ rowstart,
                                              const int* __restrict__ epos,
                                              int* __restrict__ csr) {
  int range = blockIdx.x & (NRANGE - 1);
  int lo = range * RSZ;
  int hi = lo + RSZ;
  int nblk = gridDim.x >> 3;
  int bid = blockIdx.x >> 3;
  for (int e = bid * 256 + threadIdx.x; e < NE; e += nblk * 256) {
    int d = dst[e];
    if (d >= lo && d < hi) {
      csr[rowstart[d] + epos[e]] = src[e];
    }
  }
}

// ---------------- W pre-pack into MFMA A-of-W^T fragment order (fp16) --------
// W1, pW: k = 32kk + 8q + j (natural order).
// W2:     k = 32kk + 16(j>>2) + 4q + (j&3) -- permutation that makes the
//         GEMM2 B-fragment equal the GEMM1' accumulator layout (no LDS xpose).
__global__ void k_pack(const float* __restrict__ W1, const float* __restrict__ W2,
                       const float* __restrict__ pW, ushort_t* __restrict__ wp) {
  int id = blockIdx.x * 256 + threadIdx.x;  // 7*16384
  int mtx = id >> 14;                       // 0..6
  int r = id & 16383;
  const float* src;
  int perm = 0;
  if (mtx == 6) {
    src = pW;  // natural pack: k_mm consumes memory-layout B-frags
  } else {
    int layer = mtx >> 1;
    if (mtx & 1) {
      src = W2 + layer * 16384;
      perm = 1;
    } else {
      src = W1 + layer * 16384;
    }
  }
  int j = r & 7;
  int l = (r >> 3) & 63;
  int kk = (r >> 9) & 3;
  int t = r >> 11;
  int qq = (l >> 4) & 3;
  int k = perm ? (kk * 32 + ((j >> 2) << 4) + (qq << 2) + (j & 3))
               : (kk * 32 + (qq << 3) + j);
  int n = t * 16 + (l & 15);
  wp[id] = f2h(src[k * DD + n]);
}

// ---------------- x -> fp16 h0 ----------------
__global__ void k_cast(const float* __restrict__ x, ushort_t* __restrict__ hb) {
  int i = blockIdx.x * 256 + threadIdx.x;  // over NN*DD/4
  if (i < NN * DD / 4) {
    float4 v = ((const float4*)x)[i];
    ushort4 o;
    o.x = f2h(v.x);
    o.y = f2h(v.y);
    o.z = f2h(v.z);
    o.w = f2h(v.w);
    ((ushort4*)hb)[i] = o;
  }
}

// ---- gather: z = (1+eps)*hb[n] + sum_{incoming} hb[src] (fp16) -> fp16 z ----
// Quarter-wave edge streams (round 13 memory schedule: 16 independent row-
// loads in flight). Round-14 change: the 4 loaded rows are combined with a
// pairwise v_pk_add_f16 tree (12 pk-adds/lane) and ONE fp32 accumulate per
// element per iteration -- 28 VALU ops vs 64 (the gather was going
// VALU-issue-bound: 54.9% VALUBusy in round 13). fp16 partial spans only 4
// values (~1e-3 error), fp32 across iterations.
__global__ __launch_bounds__(256) void k_gather(const ushort_t* __restrict__ hb,
                                                const int* __restrict__ rowstart,
                                                const int* __restrict__ csr,
                                                const float* __restrict__ eps, int layer,
                                                uint4* __restrict__ z) {
  int n = blockIdx.x * 4 + (threadIdx.x >> 6);
  int lane = threadIdx.x & 63;
  int g = lane >> 4;   // quarter-wave edge-stream id (0..3)
  int ii = lane & 15;  // uint4 index within the 256B row
  const uint4* hb4 = (const uint4*)hb;

  float a[8] = {0.f, 0.f, 0.f, 0.f, 0.f, 0.f, 0.f, 0.f};
  if (g == 0) {
    uint4 v = hb4[(size_t)n * 16 + ii];
    float e1 = 1.0f + eps[layer];
    a[0] = e1 * h2f((ushort_t)(v.x & 0xffffu));
    a[1] = e1 * h2f((ushort_t)(v.x >> 16));
    a[2] = e1 * h2f((ushort_t)(v.y & 0xffffu));
    a[3] = e1 * h2f((ushort_t)(v.y >> 16));
    a[4] = e1 * h2f((ushort_t)(v.z & 0xffffu));
    a[5] = e1 * h2f((ushort_t)(v.z >> 16));
    a[6] = e1 * h2f((ushort_t)(v.w & 0xffffu));
    a[7] = e1 * h2f((ushort_t)(v.w >> 16));
  }

  int s = rowstart[n], e = rowstart[n + 1];
  int k = s + g;
  for (; k + 12 < e; k += 16) {  // this stream: edges k, k+4, k+8, k+12
    int i0 = csr[k], i1 = csr[k + 4], i2 = csr[k + 8], i3 = csr[k + 12];
    uint4 v0 = hb4[(size_t)i0 * 16 + ii];
    uint4 v1 = hb4[(size_t)i1 * 16 + ii];
    uint4 v2 = hb4[(size_t)i2 * 16 + ii];
    uint4 v3 = hb4[(size_t)i3 * 16 + ii];
    // pairwise fp16 tree (v_pk_add_f16), one fp32 accumulate per element
    f16x2 p0 = (u2h2(v0.x) + u2h2(v1.x)) + (u2h2(v2.x) + u2h2(v3.x));
    f16x2 p1 = (u2h2(v0.y) + u2h2(v1.y)) + (u2h2(v2.y) + u2h2(v3.y));
    f16x2 p2 = (u2h2(v0.z) + u2h2(v1.z)) + (u2h2(v2.z) + u2h2(v3.z));
    f16x2 p3 = (u2h2(v0.w) + u2h2(v1.w)) + (u2h2(v2.w) + u2h2(v3.w));
    a[0] += (float)p0[0];
    a[1] += (float)p0[1];
    a[2] += (float)p1[0];
    a[3] += (float)p1[1];
    a[4] += (float)p2[0];
    a[5] += (float)p2[1];
    a[6] += (float)p3[0];
    a[7] += (float)p3[1];
  }
  for (; k < e; k += 4) {  // tail: exact fp32 accumulate
    uint4 v = hb4[(size_t)csr[k] * 16 + ii];
    a[0] += h2f((ushort_t)(v.x & 0xffffu));
    a[1] += h2f((ushort_t)(v.x >> 16));
    a[2] += h2f((ushort_t)(v.y & 0xffffu));
    a[3] += h2f((ushort_t)(v.y >> 16));
    a[4] += h2f((ushort_t)(v.z & 0xffffu));
    a[5] += h2f((ushort_t)(v.z >> 16));
    a[6] += h2f((ushort_t)(v.w & 0xffffu));
    a[7] += h2f((ushort_t)(v.w >> 16));
  }
#pragma unroll
  for (int j = 0; j < 8; j++) {
    a[j] += __shfl_xor(a[j], 16, 64);
    a[j] += __shfl_xor(a[j], 32, 64);
  }
  if (g == 0) {
    uint4 o;
    o.x = (unsigned)f2h(a[0]) | ((unsigned)f2h(a[1]) << 16);
    o.y = (unsigned)f2h(a[2]) | ((unsigned)f2h(a[3]) << 16);
    o.z = (unsigned)f2h(a[4]) | ((unsigned)f2h(a[5]) << 16);
    o.w = (unsigned)f2h(a[6]) | ((unsigned)f2h(a[7]) << 16);
    z[(size_t)n * 16 + ii] = o;
  }
}

// ------- fused MLP: swapped-operand, LDS-free, fp16 single-MFMA --------------
template <int LAST>
__global__ __launch_bounds__(256, 4) void k_mlp(
    const ushort_t* __restrict__ z, const ushort_t* __restrict__ W1p,
    const ushort_t* __restrict__ W2p, const float* __restrict__ b1,
    const float* __restrict__ b2, const float* __restrict__ lng,
    const float* __restrict__ lnb, const ushort_t* __restrict__ hbin,
    const ushort_t* __restrict__ hbprev1, ushort_t* __restrict__ hbout,
    const float* __restrict__ pg, const float* __restrict__ pbv,
    ushort_t* __restrict__ zo) {
  int lane = threadIdx.x & 63;
  int wid = threadIdx.x >> 6;
  int m = lane & 15;
  int q = lane >> 4;
  int node = blockIdx.x * 64 + wid * 16 + m;
  int valid = node < NN;
  int node_c = valid ? node : (NN - 1);
  size_t base = (size_t)node_c * DD;

  // z fragments (B-operand of GEMM1'), 4 k-groups
  const f16x8* Zf = (const f16x8*)(z + base);
  f16x8 zf[4];
#pragma unroll
  for (int kk = 0; kk < 4; kk++) zf[kk] = Zf[kk * 4 + q];

  // ---- GEMM1': A = W1^T frags, B = z frags. Batched loads per kk-group.
  const f16x8* W1f = (const f16x8*)W1p;
  f32x4 a1[8];
#pragma unroll
  for (int t = 0; t < 8; t++) a1[t] = (f32x4){0.f, 0.f, 0.f, 0.f};
#pragma unroll
  for (int kk = 0; kk < 4; kk++) {
    f16x8 wf[8];
#pragma unroll
    for (int t = 0; t < 8; t++) wf[t] = W1f[(t * 4 + kk) * 64 + lane];
#pragma unroll
    for (int t = 0; t < 8; t++)
      a1[t] = __builtin_amdgcn_mfma_f32_16x16x32_f16(wf[t], zf[kk], a1[t], 0, 0, 0);
  }

  // ---- bias + relu -> fp16, assembled directly into GEMM2 B-frags
  f16x8 tf[4];
#pragma unroll
  for (int t = 0; t < 8; t++) {
    float4 bb = *(const float4*)(b1 + t * 16 + q * 4);
    float bbr[4] = {bb.x, bb.y, bb.z, bb.w};
#pragma unroll
    for (int r = 0; r < 4; r++) {
      float v = fmaxf(a1[t][r] + bbr[r], 0.f);
      tf[t >> 1][(t & 1) * 4 + r] = (_Float16)v;
    }
  }

  // residual loads (fp16) issued here so latency hides under GEMM2's MFMAs
  ushort4 hr4[8];
#pragma unroll
  for (int t = 0; t < 8; t++) hr4[t] = *(const ushort4*)(hbin + base + t * 16 + q * 4);

  // ---- GEMM2': A = k-permuted W2^T frags, B = tf. Batched loads.
  const f16x8* W2f = (const f16x8*)W2p;
  f32x4 a2[8];
#pragma unroll
  for (int t = 0; t < 8; t++) a2[t] = (f32x4){0.f, 0.f, 0.f, 0.f};
#pragma unroll
  for (int g = 0; g < 4; g++) {
    f16x8 wf[8];
#pragma unroll
    for (int t = 0; t < 8; t++) wf[t] = W2f[(t * 4 + g) * 64 + lane];
#pragma unroll
    for (int t = 0; t < 8; t++)
      a2[t] = __builtin_amdgcn_mfma_f32_16x16x32_f16(wf[t], tf[g], a2[t], 0, 0, 0);
  }

  // ---- epilogue (per-node; lane holds dims 16t+4q+r of node)
  float s = 0.f, qs = 0.f;
#pragma unroll
  for (int t = 0; t < 8; t++) {
    float4 bb = *(const float4*)(b2 + t * 16 + q * 4);
    float bbr[4] = {bb.x, bb.y, bb.z, bb.w};
#pragma unroll
    for (int r = 0; r < 4; r++) {
      float u = a2[t][r] + bbr[r];
      a2[t][r] = u;
      s += u;
      qs += u * u;
    }
  }
  s += __shfl_xor(s, 16, 64);
  s += __shfl_xor(s, 32, 64);
  qs += __shfl_xor(qs, 16, 64);
  qs += __shfl_xor(qs, 32, 64);
  float mean = s * (1.0f / DD);
  float var = qs * (1.0f / DD) - mean * mean;
  float rstd = rsqrtf(var + LN_EPS);

  if (!LAST) {
#pragma unroll
    for (int t = 0; t < 8; t++) {
      float4 gg4 = *(const float4*)(lng + t * 16 + q * 4);
      float4 nb4 = *(const float4*)(lnb + t * 16 + q * 4);
      float ggr[4] = {gg4.x, gg4.y, gg4.z, gg4.w};
      float nbr[4] = {nb4.x, nb4.y, nb4.z, nb4.w};
      float hr[4] = {h2f(hr4[t].x), h2f(hr4[t].y), h2f(hr4[t].z), h2f(hr4[t].w)};
      float o[4];
#pragma unroll
      for (int r = 0; r < 4; r++) {
        float zz = (a2[t][r] - mean) * rstd * ggr[r] + nbr[r];
        o[r] = gelu_fast(zz) + hr[r];
      }
      if (valid) {
        ushort4 us;
        us.x = f2h(o[0]);
        us.y = f2h(o[1]);
        us.z = f2h(o[2]);
        us.w = f2h(o[3]);
        *(ushort4*)(hbout + base + t * 16 + q * 4) = us;
      }
    }
  } else {
    // hsum = (h1 + h2) + h3 in registers -> final pre-LN -> fp16 zo
    float w[8][4];
    float s2 = 0.f, q2 = 0.f;
#pragma unroll
    for (int t = 0; t < 8; t++) {
      float4 gg4 = *(const float4*)(lng + t * 16 + q * 4);
      float4 nb4 = *(const float4*)(lnb + t * 16 + q * 4);
      ushort4 hp4 = *(const ushort4*)(hbprev1 + base + t * 16 + q * 4);
      float ggr[4] = {gg4.x, gg4.y, gg4.z, gg4.w};
      float nbr[4] = {nb4.x, nb4.y, nb4.z, nb4.w};
      float hr[4] = {h2f(hr4[t].x), h2f(hr4[t].y), h2f(hr4[t].z), h2f(hr4[t].w)};
      float pr[4] = {h2f(hp4.x), h2f(hp4.y), h2f(hp4.z), h2f(hp4.w)};
#pragma unroll
      for (int r = 0; r < 4; r++) {
        float zz = (a2[t][r] - mean) * rstd * ggr[r] + nbr[r];
        float o = gelu_fast(zz) + hr[r];  // h3
        float wv = (pr[r] + hr[r]) + o;
        w[t][r] = wv;
        s2 += wv;
        q2 += wv * wv;
      }
    }
    s2 += __shfl_xor(s2, 16, 64);
    s2 += __shfl_xor(s2, 32, 64);
    q2 += __shfl_xor(q2, 16, 64);
    q2 += __shfl_xor(q2, 32, 64);
    float mean2 = s2 * (1.0f / DD);
    float var2 = q2 * (1.0f / DD) - mean2 * mean2;
    float rstd2 = rsqrtf(var2 + LN_EPS);
#pragma unroll
    for (int t = 0; t < 8; t++) {
      float4 pg4 = *(const float4*)(pg + t * 16 + q * 4);
      float4 pb4 = *(const float4*)(pbv + t * 16 + q * 4);
      float pgr[4] = {pg4.x, pg4.y, pg4.z, pg4.w};
      float pbr[4] = {pb4.x, pb4.y, pb4.z, pb4.w};
      float v0 = (w[t][0] - mean2) * rstd2 * pgr[0] + pbr[0];
      float v1 = (w[t][1] - mean2) * rstd2 * pgr[1] + pbr[1];
      float v2 = (w[t][2] - mean2) * rstd2 * pgr[2] + pbr[2];
      float v3 = (w[t][3] - mean2) * rstd2 * pgr[3] + pbr[3];
      if (valid) {
        ushort4 us;
        us.x = f2h(v0);
        us.y = f2h(v1);
        us.z = f2h(v2);
        us.w = f2h(v3);
        *(ushort4*)(zo + base + t * 16 + q * 4) = us;
      }
    }
  }
}

// ---------------- final GEMM: out = A*pW + pb, fp16 single-MFMA --------------
__global__ __launch_bounds__(256, 4) void k_mm(const ushort_t* __restrict__ zo,
                                               const ushort_t* __restrict__ Bp,
                                               const float* __restrict__ bias,
                                               float* __restrict__ out) {
  int lane = threadIdx.x & 63;
  int wid = threadIdx.x >> 6;
  int m = lane & 15;
  int q = lane >> 4;
  int node = blockIdx.x * 64 + wid * 16 + m;
  int valid = node < NN;
  int node_c = valid ? node : (NN - 1);
  size_t base = (size_t)node_c * DD;
  const f16x8* Zf = (const f16x8*)(zo + base);
  f16x8 zf[4];
#pragma unroll
  for (int kk = 0; kk < 4; kk++) zf[kk] = Zf[kk * 4 + q];
  const f16x8* Bf = (const f16x8*)Bp;
  f32x4 acc[8];
#pragma unroll
  for (int t = 0; t < 8; t++) acc[t] = (f32x4){0.f, 0.f, 0.f, 0.f};
#pragma unroll
  for (int kk = 0; kk < 4; kk++) {
    f16x8 wf[8];
#pragma unroll
    for (int t = 0; t < 8; t++) wf[t] = Bf[(t * 4 + kk) * 64 + lane];
#pragma unroll
    for (int t = 0; t < 8; t++)
      acc[t] = __builtin_amdgcn_mfma_f32_16x16x32_f16(wf[t], zf[kk], acc[t], 0, 0, 0);
  }
  if (valid) {
#pragma unroll
    for (int t = 0; t < 8; t++) {
      float4 bb = *(const float4*)(bias + t * 16 + q * 4);
      float4 o4;
      o4.x = acc[t][0] + bb.x;
      o4.y = acc[t][1] + bb.y;
      o4.z = acc[t][2] + bb.z;
      o4.w = acc[t][3] + bb.w;
      *(float4*)(out + base + t * 16 + q * 4) = o4;
    }
  }
}

extern "C" void kernel_launch(void* const* d_in, const int* in_sizes, int n_in, void* d_out,
                              int out_size, void* d_ws, size_t ws_size, hipStream_t stream) {
  (void)in_sizes;
  (void)n_in;
  (void)out_size;
  (void)ws_size;
  const float* x = (const float*)d_in[0];
  const int* ei = (const int*)d_in[1];
  const float* W1 = (const float*)d_in[2];
  const float* b1 = (const float*)d_in[3];
  const float* W2 = (const float*)d_in[4];
  const float* b2 = (const float*)d_in[5];
  const float* eps = (const float*)d_in[6];
  const float* lng = (const float*)d_in[7];
  const float* lnb = (const float*)d_in[8];
  const float* plg = (const float*)d_in[9];
  const float* plb = (const float*)d_in[10];
  const float* pW = (const float*)d_in[11];
  const float* pb = (const float*)d_in[12];
  float* out = (float*)d_out;

  char* ws = (char*)d_ws;
  ushort_t* hb0 = (ushort_t*)ws;
  ws += (size_t)NN * DD * 2;
  ushort_t* hb1 = (ushort_t*)ws;
  ws += (size_t)NN * DD * 2;
  ushort_t* hb2 = (ushort_t*)ws;
  ws += (size_t)NN * DD * 2;
  ushort_t* z = (ushort_t*)ws;
  ws += (size_t)NN * DD * 2;
  ushort_t* zo = (ushort_t*)ws;
  ws += (size_t)NN * DD * 2;
  ushort_t* wp = (ushort_t*)ws;
  ws += (size_t)7 * 16384 * 2;
  int* deg = (int*)ws;
  ws += (size_t)NN * 4;
  int* rowst = (int*)ws;
  ws += (size_t)(NN + 1) * 4 + 60;
  int* bsum = (int*)ws;
  ws += 512;
  int* csr = (int*)ws;
  ws += (size_t)NE * 4;
  int* epos = (int*)ws;
  ws += (size_t)NE * 4;

  const int* srcv = ei;
  const int* dstv = ei + NE;

  hipMemsetAsync(deg, 0, (size_t)NN * 4, stream);
  k_count<<<(NE + 255) / 256, 256, 0, stream>>>(dstv, deg, epos);
  k_block_sums<<<98, 256, 0, stream>>>(deg, bsum);
  k_scan_sums<<<1, 128, 0, stream>>>(bsum, 98);
  k_scan_write<<<98, 256, 0, stream>>>(deg, bsum, rowst);
  k_fill<<<4096, 256, 0, stream>>>(srcv, dstv, rowst, epos, csr);
  k_pack<<<448, 256, 0, stream>>>(W1, W2, pW, wp);
  k_cast<<<(NN * DD / 4 + 255) / 256, 256, 0, stream>>>(x, hb0);

  int mlp_grid = (NN + 63) / 64;  // 1563, 4 waves/block, 16 nodes/wave
  ushort_t* hbs[NL + 1] = {hb0, hb1, hb2, nullptr};
  for (int l = 0; l < NL; l++) {
    k_gather<<<NN / 4, 256, 0, stream>>>(hbs[l], rowst, csr, eps, l, (uint4*)z);
    if (l < NL - 1) {
      k_mlp<0><<<mlp_grid, 256, 0, stream>>>(
          z, wp + (size_t)(2 * l) * 16384, wp + (size_t)(2 * l + 1) * 16384, b1 + l * DD,
          b2 + l * DD, lng + l * DD, lnb + l * DD, hbs[l], hb1, hbs[l + 1], plg, plb, zo);
    } else {
      k_mlp<1><<<mlp_grid, 256, 0, stream>>>(
          z, wp + (size_t)(2 * l) * 16384, wp + (size_t)(2 * l + 1) * 16384, b1 + l * DD,
          b2 + l * DD, lng + l * DD, lnb + l * DD, hbs[l], hb1, hb0, plg, plb, zo);
    }
  }
  k_mm<<<mlp_grid, 256, 0, stream>>>(zo, wp + (size_t)6 * 16384, pb, out);
}